// Round 6
// baseline (493.668 us; speedup 1.0000x reference)
//
#include <hip/hip_runtime.h>

// ---------- types ----------
typedef __bf16 bf16_8 __attribute__((ext_vector_type(8)));
typedef float f32x4 __attribute__((ext_vector_type(4)));
typedef unsigned short ushort8v __attribute__((ext_vector_type(8)));
typedef unsigned short ushort4v __attribute__((ext_vector_type(4)));

#define SEQ 2048
#define HDIM 4096
#define NHEADS 32
#define NKVH 8
#define HEADD 128
#define NQKV 6144  // (32 + 2*8) * 128

__device__ __forceinline__ unsigned short f2bf(float f) {
    unsigned int u = __float_as_uint(f);
    u += 0x7fffu + ((u >> 16) & 1u);   // RNE
    return (unsigned short)(u >> 16);
}
__device__ __forceinline__ float bf2f(unsigned short v) {
    return __uint_as_float(((unsigned int)v) << 16);
}

#if defined(__has_builtin)
#if __has_builtin(__builtin_amdgcn_exp2f)
#define EXP2(x) __builtin_amdgcn_exp2f(x)
#endif
#endif
#ifndef EXP2
#define EXP2(x) __expf(0.69314718055994531f * (x))
#endif

typedef __attribute__((address_space(1))) void as1_void;
typedef __attribute__((address_space(3))) void as3_void;
__device__ __forceinline__ void gload16(const unsigned short* g, unsigned short* l) {
    __builtin_amdgcn_global_load_lds((as1_void*)g, (as3_void*)l, 16, 0, 0);
}

// ---------- kernel 1: fp32 -> bf16 straight convert ----------
__global__ void k_f32_to_bf16(const float* __restrict__ in, unsigned short* __restrict__ out, int n) {
    int i = (blockIdx.x * blockDim.x + threadIdx.x) * 4;
    if (i >= n) return;
    float4 v = *reinterpret_cast<const float4*>(in + i);
    ushort4v o = { f2bf(v.x), f2bf(v.y), f2bf(v.z), f2bf(v.w) };
    *reinterpret_cast<ushort4v*>(out + i) = o;
}

// ---------- kernel 2: fp32 [K][N] -> bf16 [N][K] transpose+convert ----------
__global__ void k_transpose_f32_to_bf16(const float* __restrict__ in, unsigned short* __restrict__ out,
                                        int K, int N) {
    __shared__ unsigned short tile[64][72];
    int k0 = blockIdx.y * 64, n0 = blockIdx.x * 64;
    int t = threadIdx.x;
    int r = t >> 2;
    int cs = (t & 3) * 16;
    int sw = (r >> 4) * 16;
    const float* src = in + (size_t)(k0 + r) * N + n0 + cs;
#pragma unroll
    for (int j = 0; j < 16; j += 4) {
        float4 v = *reinterpret_cast<const float4*>(src + j);
        tile[r][(cs + j + 0) ^ sw] = f2bf(v.x);
        tile[r][(cs + j + 1) ^ sw] = f2bf(v.y);
        tile[r][(cs + j + 2) ^ sw] = f2bf(v.z);
        tile[r][(cs + j + 3) ^ sw] = f2bf(v.w);
    }
    __syncthreads();
    int rr = t >> 2;
    int ks = (t & 3) * 16;
    unsigned short tmp[16];
#pragma unroll
    for (int i = 0; i < 16; i++) tmp[i] = tile[ks + i][rr ^ (((ks + i) >> 4) * 16)];
    unsigned short* dst = out + (size_t)(n0 + rr) * K + k0 + ks;
    *reinterpret_cast<ushort8v*>(dst) = *reinterpret_cast<const ushort8v*>(tmp);
    *reinterpret_cast<ushort8v*>(dst + 8) = *reinterpret_cast<const ushort8v*>(tmp + 8);
}

// ---------- kernel 2b: bf16 [R][C] tile transpose (strided view), same swizzle ----------
__global__ void k_transpose_bf16(const unsigned short* __restrict__ in, unsigned short* __restrict__ out,
                                 int inStride, int outStride) {
    __shared__ unsigned short tile[64][72];
    int r0 = blockIdx.y * 64, c0 = blockIdx.x * 64;
    int t = threadIdx.x;
    int r = t >> 2;
    int cs = (t & 3) * 16;
    int csw = cs ^ ((r >> 4) * 16);
    const unsigned short* src = in + (size_t)(r0 + r) * inStride + c0 + cs;
    *reinterpret_cast<ushort8v*>(&tile[r][csw])     = *reinterpret_cast<const ushort8v*>(src);
    *reinterpret_cast<ushort8v*>(&tile[r][csw + 8]) = *reinterpret_cast<const ushort8v*>(src + 8);
    __syncthreads();
    int rr = t >> 2;
    int ks = (t & 3) * 16;
    unsigned short tmp[16];
#pragma unroll
    for (int i = 0; i < 16; i++) tmp[i] = tile[ks + i][rr ^ (((ks + i) >> 4) * 16)];
    unsigned short* dst = out + (size_t)(c0 + rr) * outStride + r0 + ks;
    *reinterpret_cast<ushort8v*>(dst) = *reinterpret_cast<const ushort8v*>(tmp);
    *reinterpret_cast<ushort8v*>(dst + 8) = *reinterpret_cast<const ushort8v*>(tmp + 8);
}

// ---------- kernel 3: 8-phase (BN=256) / 4-phase (BN=128) bf16 GEMM, BM=256 ----------
// Unchanged (control).

#define RG(BUF, KH) (smem + ((BUF) * 2 + (KH)) * PR)

#define STAGE_A(TILE, KH) do { if ((TILE) < NT) {                                        \
    size_t kb_ = (size_t)(TILE) * 128 + (size_t)((KH) * 64);                             \
    char* d_ = RG((TILE) & 1, KH) + wby;                                                 \
    gload16((const unsigned short*)(srcA0 + kb_), (unsigned short*)d_);                  \
    gload16((const unsigned short*)(srcA1 + kb_), (unsigned short*)(d_ + 8192));         \
  } } while (0)

#define STAGE_B(TILE, KH) do { if ((TILE) < NT) {                                        \
    size_t kb_ = (size_t)(TILE) * 128 + (size_t)((KH) * 64);                             \
    char* d_ = RG((TILE) & 1, KH) + 16384 + wby;                                         \
    gload16((const unsigned short*)(srcB0 + kb_), (unsigned short*)d_);                  \
    if constexpr (BN == 256)                                                             \
        gload16((const unsigned short*)(srcB1 + kb_), (unsigned short*)(d_ + 8192));     \
  } } while (0)

#define STAGE_AB(TILE, KH) do { STAGE_A(TILE, KH); STAGE_B(TILE, KH); } while (0)

#define VMW_N() do {                                                                     \
    if constexpr (BN == 256) asm volatile("s_waitcnt vmcnt(8)" ::: "memory");            \
    else                     asm volatile("s_waitcnt vmcnt(6)" ::: "memory");            \
  } while (0)

#define TAILVM() do {                                                                    \
    if (tail) asm volatile("s_waitcnt vmcnt(0)" ::: "memory");                           \
    else      VMW_N();                                                                   \
  } while (0)

#define VM_T(NT_, TL_) do {                                                              \
    if (tail) asm volatile("s_waitcnt vmcnt(" #TL_ ")" ::: "memory");                    \
    else      asm volatile("s_waitcnt vmcnt(" #NT_ ")" ::: "memory");                    \
  } while (0)

#define PHASE_G(PB, PKH, MBASE, MCNT, DOB, STAGE_STMT, VM_STMT) do {                     \
    const char* ab_ = RG(PB, PKH);                                                       \
    bf16_8 av_[MCNT];                                                                    \
    _Pragma("unroll")                                                                    \
    for (int mi_ = 0; mi_ < (MCNT); ++mi_)                                               \
        av_[mi_] = *(const bf16_8*)(ab_ + offA[(MBASE) + mi_]);                          \
    if (DOB) {                                                                           \
        _Pragma("unroll")                                                                \
        for (int nj_ = 0; nj_ < 4; ++nj_)                                                \
            bv[nj_] = *(const bf16_8*)(ab_ + 16384 + offB[nj_]);                         \
    }                                                                                    \
    STAGE_STMT;                                                                          \
    VM_STMT;                                                                             \
    __builtin_amdgcn_s_barrier();                                                        \
    __builtin_amdgcn_s_setprio(1);                                                       \
    _Pragma("unroll")                                                                    \
    for (int mi_ = 0; mi_ < (MCNT); ++mi_) {                                             \
        _Pragma("unroll")                                                                \
        for (int nj_ = 0; nj_ < 4; ++nj_)                                                \
            acc[(MBASE) + mi_][nj_] = __builtin_amdgcn_mfma_f32_16x16x32_bf16(           \
                av_[mi_], bv[nj_], acc[(MBASE) + mi_][nj_], 0, 0, 0);                    \
    }                                                                                    \
    __builtin_amdgcn_s_setprio(0);                                                       \
    asm volatile("s_waitcnt lgkmcnt(0)" ::: "memory");                                   \
    __builtin_amdgcn_s_barrier();                                                        \
  } while (0)

template <int BN, int WM, int WN, bool OUT_BF16, bool FUSE_T>
__global__ __launch_bounds__(512, 2) void k_gemm256(
    const unsigned short* __restrict__ A,   // [M][K] bf16
    const unsigned short* __restrict__ Bt,  // [N][K] bf16
    void* __restrict__ Cv,                  // [M][N]
    int N, int K, int nwgemm, int ntn,
    const float* __restrict__ TPin, unsigned short* __restrict__ TPout)
{
    extern __shared__ char smem[];
    constexpr int PWR = 256 / WM;        // per-wave rows of C
    constexpr int PWC = BN / WN;         // per-wave cols of C
    constexpr int MF  = PWR / 16;        // m fragments per wave
    constexpr int MF2 = MF / 2;
    constexpr int PR  = 16384 + BN * 64; // bytes per (buf,khalf) region: A 16K + B
    int t = threadIdx.x;

    if constexpr (FUSE_T) {
        if ((int)blockIdx.x >= nwgemm) {
            int tb = blockIdx.x - nwgemm;        // 0..63
            int half = t >> 8, lt = t & 255;
            unsigned short* tile = (unsigned short*)smem + half * (64 * 72);
            int r = lt >> 2, cs = (lt & 3) * 16, sw = (r >> 4) * 16;
            for (int i = 0; i < 32; ++i) {
                int tau = tb * 64 + i * 2 + half;
                int n0 = (tau & 63) * 64, k0 = (tau >> 6) * 64;
                const float* src = TPin + (size_t)(k0 + r) * 4096 + n0 + cs;
#pragma unroll
                for (int j = 0; j < 16; j += 4) {
                    float4 v = *reinterpret_cast<const float4*>(src + j);
                    tile[r * 72 + ((cs + j + 0) ^ sw)] = f2bf(v.x);
                    tile[r * 72 + ((cs + j + 1) ^ sw)] = f2bf(v.y);
                    tile[r * 72 + ((cs + j + 2) ^ sw)] = f2bf(v.z);
                    tile[r * 72 + ((cs + j + 3) ^ sw)] = f2bf(v.w);
                }
                __syncthreads();
                unsigned short tmp[16];
#pragma unroll
                for (int q = 0; q < 16; q++)
                    tmp[q] = tile[(cs + q) * 72 + (r ^ (((cs + q) >> 4) * 16))];
                unsigned short* dst = TPout + (size_t)(n0 + r) * 4096 + k0 + cs;
                *reinterpret_cast<ushort8v*>(dst) = *reinterpret_cast<const ushort8v*>(tmp);
                *reinterpret_cast<ushort8v*>(dst + 8) = *reinterpret_cast<const ushort8v*>(tmp + 8);
                __syncthreads();
            }
            return;
        }
    }

    const int NT = K >> 6;               // K-tiles of 64
    int bid = blockIdx.x;
    int cpx = nwgemm >> 3;               // XCD-chunked bijective swizzle (nwgemm % 8 == 0)
    int sw_ = (bid & 7) * cpx + (bid >> 3);
    int tm = sw_ / ntn, tn = sw_ % ntn;
    int gm0 = tm << 8, gn0 = tn * BN;

    int w = t >> 6, lane = t & 63;
    int l15 = lane & 15, quad = lane >> 4;
    int wr = w / WN, wc = w % WN;
    int wby = w << 10;

    // per-lane swizzled ds_read byte offsets within a region
    int offA[MF], offB[4];
#pragma unroll
    for (int mh = 0; mh < 2; mh++)
#pragma unroll
        for (int mi = 0; mi < MF2; mi++) {
            int row = wr * PWR + mh * (PWR / 2) + mi * 16 + l15;
            offA[mh * MF2 + mi] = row * 64 + ((quad ^ ((row >> 1) & 3)) << 4);
        }
#pragma unroll
    for (int nj = 0; nj < 4; nj++) {
        int row = wc * PWC + nj * 16 + l15;
        offB[nj] = row * 64 + ((quad ^ ((row >> 1) & 3)) << 4);
    }

    // staging: linear LDS dest, inverse-swizzled global source
    int srow0 = t >> 2;                          // 0..127
    int sslot = (t & 3) ^ ((srow0 >> 1) & 3);
    const char* srcA0 = (const char*)A  + ((size_t)(gm0 + srow0)       * K + sslot * 8) * 2;
    const char* srcA1 = (const char*)A  + ((size_t)(gm0 + srow0 + 128) * K + sslot * 8) * 2;
    const char* srcB0 = (const char*)Bt + ((size_t)(gn0 + srow0)       * K + sslot * 8) * 2;
    const char* srcB1 = (BN == 256)
        ? (const char*)Bt + ((size_t)(gn0 + srow0 + 128) * K + sslot * 8) * 2
        : srcB0;

    f32x4 acc[MF][4] = {};
    bf16_8 bv[4];

    const int NITER = K >> 7;

    if constexpr (BN == 256) {
        // prologue: T0 fully + T1 khalf0 (12 loads)
        STAGE_A(0, 0); STAGE_B(0, 0);
        STAGE_A(0, 1); STAGE_B(0, 1);
        STAGE_A(1, 0); STAGE_B(1, 0);
        VMW_N();
        __builtin_amdgcn_s_barrier();
        for (int it = 0; it < NITER; ++it) {
            int T1 = 2 * it + 1, T2 = T1 + 1, T3 = T1 + 2;
            bool tail = (it == NITER - 1);
            PHASE_G(0, 0, 0,   MF2, 1, STAGE_A(T1, 1), ((void)0));
            PHASE_G(0, 0, MF2, MF2, 0, STAGE_B(T1, 1), VMW_N());
            PHASE_G(0, 1, 0,   MF2, 1, STAGE_A(T2, 0), ((void)0));
            PHASE_G(0, 1, MF2, MF2, 0, STAGE_B(T2, 0), TAILVM());
            PHASE_G(1, 0, 0,   MF2, 1, STAGE_A(T2, 1), ((void)0));
            PHASE_G(1, 0, MF2, MF2, 0, STAGE_B(T2, 1), VMW_N());
            PHASE_G(1, 1, 0,   MF2, 1, STAGE_A(T3, 0), ((void)0));
            PHASE_G(1, 1, MF2, MF2, 0, STAGE_B(T3, 0), VMW_N());
        }
    } else {
        // prologue: 3 stage units (9 loads)
        STAGE_AB(0, 0); STAGE_AB(0, 1); STAGE_AB(1, 0);
        asm volatile("s_waitcnt vmcnt(6)" ::: "memory");
        __builtin_amdgcn_s_barrier();
        for (int it = 0; it < NITER; ++it) {
            int T1 = 2 * it + 1, T2 = T1 + 1, T3 = T1 + 2;
            bool tail = (it == NITER - 1);
            PHASE_G(0, 0, 0, MF, 1, STAGE_AB(T1, 1),
                    asm volatile("s_waitcnt vmcnt(6)" ::: "memory"));
            PHASE_G(0, 1, 0, MF, 1, STAGE_AB(T2, 0), VM_T(6, 3));
            PHASE_G(1, 0, 0, MF, 1, STAGE_AB(T2, 1), VM_T(6, 0));
            PHASE_G(1, 1, 0, MF, 1, STAGE_AB(T3, 0), VM_T(6, 0));
        }
    }

    // epilogue
    int crow = gm0 + wr * PWR + quad * 4;
    int ccol = gn0 + wc * PWC + l15;
#pragma unroll
    for (int m = 0; m < MF; m++)
#pragma unroll
        for (int nj = 0; nj < 4; nj++)
#pragma unroll
            for (int r = 0; r < 4; r++) {
                size_t idx = (size_t)(crow + m * 16 + r) * N + (ccol + nj * 16);
                float v = acc[m][nj][r];
                if (OUT_BF16) ((unsigned short*)Cv)[idx] = f2bf(v);
                else          ((float*)Cv)[idx] = v;
            }
}

#undef RG
#undef STAGE_A
#undef STAGE_B
#undef STAGE_AB
#undef VMW_N
#undef TAILVM
#undef VM_T
#undef PHASE_G

// ---------- kernel 4: RoPE + head split; Q pre-scaled by (1/sqrt(128))*log2(e) ----------
__global__ void k_rope_split(const unsigned short* __restrict__ qkv,
                             unsigned short* __restrict__ Qb,
                             unsigned short* __restrict__ Kb)
{
    int wid = blockIdx.x * 4 + (threadIdx.x >> 6);
    int lane = threadIdx.x & 63;
    int head = wid % 40;
    int s = wid / 40;
    const unsigned short* src = qkv + (size_t)s * NQKV + head * HEADD;
    float x1 = bf2f(src[lane]);
    float x2 = bf2f(src[lane + 64]);
    float inv = __expf(-(float)lane * 0.14391156831212787f);
    float ang = (float)s * inv;
    float sn, c;
    __sincosf(ang, &sn, &c);
    float o1 = x1 * c - x2 * sn;
    float o2 = x1 * sn + x2 * c;
    unsigned short* dst;
    if (head < 32) {
        const float s2 = 0.12752908270648427f;  // (1/sqrt(128)) * log2(e) folded into Q
        o1 *= s2; o2 *= s2;
        dst = Qb + ((size_t)head * SEQ + s) * HEADD;
    } else {
        dst = Kb + ((size_t)(head - 32) * SEQ + s) * HEADD;
    }
    dst[lane] = f2bf(o1);
    dst[lane + 64] = f2bf(o2);
}

// ---------- kernel 5: pipelined causal flash attention, 128-row super-tiles ----------
// grid (8, 32); 512 thr / 8 waves; super-tile pair (b, 15-b) -> uniform 34 kv-iters.
// LDS = 2x32KB K/V dbuf + 16KB swizzled Ps = 81920 B EXACTLY -> 2 blocks/CU.
// Ps per-wave [16][64] ushort, col' = col ^ ((l15&7)<<3): involution applied to both the
// 4-ushort writes and 8-ushort reads (swizzle bits >=3 only; max LDS byte = 81919).
// launch_bounds(512,4) caps VGPR at 128 so the 2-block occupancy is granted.
// (setprio pairs removed this round: de-risk while isolating the occupancy change.)
__global__ __launch_bounds__(512, 4) void k_attention(
    const unsigned short* __restrict__ Qb,  // [32][S][128], pre-scaled
    const unsigned short* __restrict__ Kb,  // [8][S][128]
    const unsigned short* __restrict__ Vt,  // [8*128][S]  (V transposed)
    unsigned short* __restrict__ Ob)        // [S][4096]
{
    extern __shared__ char smem[];          // [2][32768] K(16K)+V(16K); Ps @65536 (16K)
    int h = blockIdx.y, hkv = h >> 2;
    int b = blockIdx.x;                     // 0..7
    int t = threadIdx.x;
    int w = t >> 6, lane = t & 63, l15 = lane & 15, quad = lane >> 4;
    int x7 = l15 & 7;
    int psw = x7 << 3;                      // Ps col swizzle (ushort units)

    const char* kbase = (const char*)(Kb + (size_t)hkv * SEQ * HEADD);
    const char* vbase = (const char*)(Vt + (size_t)hkv * HEADD * SEQ);

    // staging constants: K rows 256B (16 slots), V rows 128B (8 slots)
    int rK0 = w * 4 + (lane >> 4), rK1 = rK0 + 32;
    size_t SK0 = (size_t)rK0 * 256 + (size_t)(((lane & 15) ^ (rK0 & 7)) << 4);
    size_t SK1 = (size_t)rK1 * 256 + (size_t)(((lane & 15) ^ (rK1 & 7)) << 4);
    int rV0 = w * 8 + (lane >> 3), rV1 = rV0 + 64;
    size_t SV0 = (size_t)rV0 * 4096 + (size_t)(((lane & 7) ^ (rV0 & 7)) << 4);
    size_t SV1 = (size_t)rV1 * 4096 + (size_t)(((lane & 7) ^ (rV1 & 7)) << 4);

    const int nA = 2 * b + 2;
    const int NI = 34;
    const int qm0B = (15 - b) * 128 + w * 16;
    int qm0 = b * 128 + w * 16;             // phase-A wave q-base
    int qg  = qm0 + l15;

    bf16_8 aq[4];
    {
        const unsigned short* qp = Qb + ((size_t)h * SEQ + qg) * HEADD + quad * 8;
#pragma unroll
        for (int kk = 0; kk < 4; kk++)
            aq[kk] = *reinterpret_cast<const bf16_8*>(qp + kk * 32);
    }

    f32x4 o[8] = {};
    float l_ = 0.f;

    // prologue: stage tile 0 -> region 0
    {
        char* dK = smem + w * 1024;
        gload16((const unsigned short*)(kbase + SK0), (unsigned short*)dK);
        gload16((const unsigned short*)(kbase + SK1), (unsigned short*)(dK + 8192));
        char* dV = smem + 16384 + w * 1024;
        gload16((const unsigned short*)(vbase + SV0), (unsigned short*)dV);
        gload16((const unsigned short*)(vbase + SV1), (unsigned short*)(dV + 8192));
    }

    for (int ii = 0; ii < NI; ++ii) {
        if (ii + 1 < NI) {
            int j = ii + 1;
            int kvn = (j < nA ? j : j - nA) << 6;
            const char* kb = kbase + (size_t)kvn * 256;
            const char* vb = vbase + (size_t)kvn * 2;
            char* dK = smem + (j & 1) * 32768 + w * 1024;
            gload16((const unsigned short*)(kb + SK0), (unsigned short*)dK);
            gload16((const unsigned short*)(kb + SK1), (unsigned short*)(dK + 8192));
            char* dV = smem + (j & 1) * 32768 + 16384 + w * 1024;
            gload16((const unsigned short*)(vb + SV0), (unsigned short*)dV);
            gload16((const unsigned short*)(vb + SV1), (unsigned short*)(dV + 8192));
            asm volatile("s_waitcnt vmcnt(4)" ::: "memory");
        } else {
            asm volatile("s_waitcnt vmcnt(0)" ::: "memory");
        }
        __builtin_amdgcn_s_barrier();

        if (ii == nA) {
            // phase-A epilogue; then switch to phase-B q-tile
            float lr = l_;
            lr += __shfl_xor(lr, 16, 64);
            lr += __shfl_xor(lr, 32, 64);
            float rinv = 1.0f / lr;
            unsigned short* orow = Ob + (size_t)qg * (NHEADS * HEADD) + h * HEADD + quad * 4;
#pragma unroll
            for (int dt = 0; dt < 8; dt++) {
                ushort4v pk = { f2bf(o[dt][0] * rinv), f2bf(o[dt][1] * rinv),
                                f2bf(o[dt][2] * rinv), f2bf(o[dt][3] * rinv) };
                *reinterpret_cast<ushort4v*>(orow + dt * 16) = pk;
            }
            qm0 = qm0B; qg = qm0B + l15;
            const unsigned short* qp = Qb + ((size_t)h * SEQ + qg) * HEADD + quad * 8;
#pragma unroll
            for (int kk = 0; kk < 4; kk++)
                aq[kk] = *reinterpret_cast<const bf16_8*>(qp + kk * 32);
#pragma unroll
            for (int dt = 0; dt < 8; dt++) o[dt] = (f32x4){0.f, 0.f, 0.f, 0.f};
            l_ = 0.f;
        }

        int kv0 = (ii < nA ? ii : ii - nA) << 6;
        const unsigned short* Kbuf = (const unsigned short*)(smem + (ii & 1) * 32768);
        const unsigned short* Vbuf = Kbuf + 8192;

        if (kv0 <= qm0 + 15) {
            f32x4 sc[4];
#pragma unroll
            for (int nt = 0; nt < 4; nt++) {
                f32x4 z = {};
#pragma unroll
                for (int kk = 0; kk < 4; kk++) {
                    bf16_8 bk = *reinterpret_cast<const bf16_8*>(
                        &Kbuf[(nt * 16 + l15) * 128 + (((kk * 4 + quad) ^ x7) << 3)]);
                    z = __builtin_amdgcn_mfma_f32_16x16x32_bf16(bk, aq[kk], z, 0, 0, 0);
                }
                sc[nt] = z;
            }
            bool needMask = (kv0 + 63 > qm0);
#pragma unroll
            for (int nt = 0; nt < 4; nt++)
#pragma unroll
                for (int r = 0; r < 4; r++) {
                    float a = sc[nt][r] - 12.0f;   // fixed shift, no running max
                    if (needMask) {
                        int kg = kv0 + nt * 16 + quad * 4 + r;
                        if (kg > qg) a = -1000.0f;
                    }
                    float p = EXP2(a);
                    sc[nt][r] = p;
                    l_ += p;
                }
            // P^T round-trip via swizzled per-wave [16][64] Ps (C-layout -> B-frag layout)
            unsigned short* prow = (unsigned short*)(smem + 65536 + w * 2048) + l15 * 64;
#pragma unroll
            for (int nt = 0; nt < 4; nt++) {
                ushort4v pk = { f2bf(sc[nt][0]), f2bf(sc[nt][1]), f2bf(sc[nt][2]), f2bf(sc[nt][3]) };
                *reinterpret_cast<ushort4v*>(prow + ((nt * 16 + quad * 4) ^ psw)) = pk;
            }
            asm volatile("s_waitcnt lgkmcnt(0)" ::: "memory");
            bf16_8 pf[2];
#pragma unroll
            for (int kk = 0; kk < 2; kk++)
                pf[kk] = *reinterpret_cast<const bf16_8*>(prow + ((kk * 32 + quad * 8) ^ psw));
#pragma unroll
            for (int dt = 0; dt < 8; dt++)
#pragma unroll
                for (int kk = 0; kk < 2; kk++) {
                    bf16_8 av = *reinterpret_cast<const bf16_8*>(
                        &Vbuf[(dt * 16 + l15) * 64 + (((kk * 4 + quad) ^ x7) << 3)]);
                    o[dt] = __builtin_amdgcn_mfma_f32_16x16x32_bf16(av, pf[kk], o[dt], 0, 0, 0);
                }
        }
        asm volatile("s_waitcnt lgkmcnt(0)" ::: "memory");
        __builtin_amdgcn_s_barrier();
    }

    // phase-B epilogue
    l_ += __shfl_xor(l_, 16, 64);
    l_ += __shfl_xor(l_, 32, 64);
    float rinv = 1.0f / l_;
    unsigned short* orow = Ob + (size_t)qg * (NHEADS * HEADD) + h * HEADD + quad * 4;
#pragma unroll
    for (int dt = 0; dt < 8; dt++) {
        ushort4v pk = { f2bf(o[dt][0] * rinv), f2bf(o[dt][1] * rinv),
                        f2bf(o[dt][2] * rinv), f2bf(o[dt][3] * rinv) };
        *reinterpret_cast<ushort4v*>(orow + dt * 16) = pk;
    }
}

// ---------- launch ----------
extern "C" void kernel_launch(void* const* d_in, const int* in_sizes, int n_in,
                              void* d_out, int out_size, void* d_ws, size_t ws_size,
                              hipStream_t stream) {
    const float* hs    = (const float*)d_in[0];
    const float* w_qkv = (const float*)d_in[1];
    const float* w_o   = (const float*)d_in[2];

    static bool s_attr_set = false;
    if (!s_attr_set) {
        hipFuncSetAttribute(reinterpret_cast<const void*>(k_gemm256<256, 2, 4, true, true>),
                            hipFuncAttributeMaxDynamicSharedMemorySize, 131072);
        hipFuncSetAttribute(reinterpret_cast<const void*>(k_gemm256<128, 4, 2, false, false>),
                            hipFuncAttributeMaxDynamicSharedMemorySize, 131072);
        hipFuncSetAttribute(reinterpret_cast<const void*>(k_attention),
                            hipFuncAttributeMaxDynamicSharedMemorySize, 131072);
        s_attr_set = true;
    }

    char* ws = (char*)d_ws;
    size_t off = 0;
    auto alloc = [&](size_t bytes) -> void* {
        void* p = ws + off;
        off += (bytes + 255) & ~(size_t)255;
        return p;
    };
    unsigned short* Xb    = (unsigned short*)alloc((size_t)SEQ * HDIM * 2);
    unsigned short* R1    = (unsigned short*)alloc((size_t)NQKV * HDIM * 2);
    unsigned short* Wot   = (unsigned short*)alloc((size_t)HDIM * HDIM * 2);
    unsigned short* QKVb  = (unsigned short*)alloc((size_t)SEQ * NQKV * 2);
    unsigned short* Wqkvt = R1;
    unsigned short* Qb = R1;
    unsigned short* Kb = Qb + (size_t)NHEADS * SEQ * HEADD;
    unsigned short* Vt = Kb + (size_t)NKVH * SEQ * HEADD;
    unsigned short* AOb = Xb;

    k_f32_to_bf16<<<(SEQ * HDIM) / 1024, 256, 0, stream>>>(hs, Xb, SEQ * HDIM);
    k_transpose_f32_to_bf16<<<dim3(NQKV / 64, HDIM / 64), 256, 0, stream>>>(w_qkv, Wqkvt, HDIM, NQKV);
    // GEMM1: 192 gemm blocks + 64 blocks doing the w_o transpose on otherwise-idle CUs
    k_gemm256<256, 2, 4, true, true><<<dim3(256), dim3(512), 131072, stream>>>(
        Xb, Wqkvt, QKVb, NQKV, HDIM, 192, NQKV / 256, w_o, Wot);
    k_rope_split<<<(SEQ * 40) / 4, 256, 0, stream>>>(QKVb, Qb, Kb);
    k_transpose_bf16<<<dim3((NKVH * HEADD) / 64, SEQ / 64), 256, 0, stream>>>(
        QKVb + (size_t)(NHEADS + NKVH) * HEADD, Vt, NQKV, SEQ);
    // attention: 256 wgs, 81920 B LDS -> 2 blocks/CU
    k_attention<<<dim3(8, NHEADS), dim3(512), 81920, stream>>>(Qb, Kb, Vt, AOb);
    // GEMM2: 256x128 tiles, 4-phase full-M schedule, 256 wgs exactly
    k_gemm256<128, 4, 2, false, false><<<dim3(256), dim3(512), 98304, stream>>>(
        AOb, Wot, d_out, HDIM, HDIM, 256, HDIM / 128, nullptr, nullptr);
}

// Round 7
// 471.849 us; speedup vs baseline: 1.0462x; 1.0462x over previous
//
#include <hip/hip_runtime.h>

// ---------- types ----------
typedef __bf16 bf16_8 __attribute__((ext_vector_type(8)));
typedef float f32x4 __attribute__((ext_vector_type(4)));
typedef unsigned short ushort8v __attribute__((ext_vector_type(8)));
typedef unsigned short ushort4v __attribute__((ext_vector_type(4)));

#define SEQ 2048
#define HDIM 4096
#define NHEADS 32
#define NKVH 8
#define HEADD 128
#define NQKV 6144  // (32 + 2*8) * 128

__device__ __forceinline__ unsigned short f2bf(float f) {
    unsigned int u = __float_as_uint(f);
    u += 0x7fffu + ((u >> 16) & 1u);   // RNE
    return (unsigned short)(u >> 16);
}
__device__ __forceinline__ float bf2f(unsigned short v) {
    return __uint_as_float(((unsigned int)v) << 16);
}

#if defined(__has_builtin)
#if __has_builtin(__builtin_amdgcn_exp2f)
#define EXP2(x) __builtin_amdgcn_exp2f(x)
#endif
#endif
#ifndef EXP2
#define EXP2(x) __expf(0.69314718055994531f * (x))
#endif

typedef __attribute__((address_space(1))) void as1_void;
typedef __attribute__((address_space(3))) void as3_void;
__device__ __forceinline__ void gload16(const unsigned short* g, unsigned short* l) {
    __builtin_amdgcn_global_load_lds((as1_void*)g, (as3_void*)l, 16, 0, 0);
}

// ---------- kernel 1: fp32 -> bf16 straight convert ----------
__global__ void k_f32_to_bf16(const float* __restrict__ in, unsigned short* __restrict__ out, int n) {
    int i = (blockIdx.x * blockDim.x + threadIdx.x) * 4;
    if (i >= n) return;
    float4 v = *reinterpret_cast<const float4*>(in + i);
    ushort4v o = { f2bf(v.x), f2bf(v.y), f2bf(v.z), f2bf(v.w) };
    *reinterpret_cast<ushort4v*>(out + i) = o;
}

// ---------- kernel 2: fp32 [K][N] -> bf16 [N][K] transpose+convert ----------
__global__ void k_transpose_f32_to_bf16(const float* __restrict__ in, unsigned short* __restrict__ out,
                                        int K, int N) {
    __shared__ unsigned short tile[64][72];
    int k0 = blockIdx.y * 64, n0 = blockIdx.x * 64;
    int t = threadIdx.x;
    int r = t >> 2;
    int cs = (t & 3) * 16;
    int sw = (r >> 4) * 16;
    const float* src = in + (size_t)(k0 + r) * N + n0 + cs;
#pragma unroll
    for (int j = 0; j < 16; j += 4) {
        float4 v = *reinterpret_cast<const float4*>(src + j);
        tile[r][(cs + j + 0) ^ sw] = f2bf(v.x);
        tile[r][(cs + j + 1) ^ sw] = f2bf(v.y);
        tile[r][(cs + j + 2) ^ sw] = f2bf(v.z);
        tile[r][(cs + j + 3) ^ sw] = f2bf(v.w);
    }
    __syncthreads();
    int rr = t >> 2;
    int ks = (t & 3) * 16;
    unsigned short tmp[16];
#pragma unroll
    for (int i = 0; i < 16; i++) tmp[i] = tile[ks + i][rr ^ (((ks + i) >> 4) * 16)];
    unsigned short* dst = out + (size_t)(n0 + rr) * K + k0 + ks;
    *reinterpret_cast<ushort8v*>(dst) = *reinterpret_cast<const ushort8v*>(tmp);
    *reinterpret_cast<ushort8v*>(dst + 8) = *reinterpret_cast<const ushort8v*>(tmp + 8);
}

// ---------- kernel 2b: bf16 [R][C] tile transpose (strided view), same swizzle ----------
__global__ void k_transpose_bf16(const unsigned short* __restrict__ in, unsigned short* __restrict__ out,
                                 int inStride, int outStride) {
    __shared__ unsigned short tile[64][72];
    int r0 = blockIdx.y * 64, c0 = blockIdx.x * 64;
    int t = threadIdx.x;
    int r = t >> 2;
    int cs = (t & 3) * 16;
    int csw = cs ^ ((r >> 4) * 16);
    const unsigned short* src = in + (size_t)(r0 + r) * inStride + c0 + cs;
    *reinterpret_cast<ushort8v*>(&tile[r][csw])     = *reinterpret_cast<const ushort8v*>(src);
    *reinterpret_cast<ushort8v*>(&tile[r][csw + 8]) = *reinterpret_cast<const ushort8v*>(src + 8);
    __syncthreads();
    int rr = t >> 2;
    int ks = (t & 3) * 16;
    unsigned short tmp[16];
#pragma unroll
    for (int i = 0; i < 16; i++) tmp[i] = tile[ks + i][rr ^ (((ks + i) >> 4) * 16)];
    unsigned short* dst = out + (size_t)(c0 + rr) * outStride + r0 + ks;
    *reinterpret_cast<ushort8v*>(dst) = *reinterpret_cast<const ushort8v*>(tmp);
    *reinterpret_cast<ushort8v*>(dst + 8) = *reinterpret_cast<const ushort8v*>(tmp + 8);
}

// ---------- kernel 3: 8-phase (BN=256) / 4-phase (BN=128) bf16 GEMM, BM=256 ----------
// Schedules unchanged from round 3. NEW: 2D XCD sub-block swizzle — each XCD owns a
// TMX x TNX tile block so its per-K-slice A/B working set (~256-320 KB) is L2-resident;
// the old 1D chunking gave each XCD one full tile-row (entire B panel -> L3-latency
// loads that the 2-phase-deep vmcnt pipeline cannot cover).

#define RG(BUF, KH) (smem + ((BUF) * 2 + (KH)) * PR)

#define STAGE_A(TILE, KH) do { if ((TILE) < NT) {                                        \
    size_t kb_ = (size_t)(TILE) * 128 + (size_t)((KH) * 64);                             \
    char* d_ = RG((TILE) & 1, KH) + wby;                                                 \
    gload16((const unsigned short*)(srcA0 + kb_), (unsigned short*)d_);                  \
    gload16((const unsigned short*)(srcA1 + kb_), (unsigned short*)(d_ + 8192));         \
  } } while (0)

#define STAGE_B(TILE, KH) do { if ((TILE) < NT) {                                        \
    size_t kb_ = (size_t)(TILE) * 128 + (size_t)((KH) * 64);                             \
    char* d_ = RG((TILE) & 1, KH) + 16384 + wby;                                         \
    gload16((const unsigned short*)(srcB0 + kb_), (unsigned short*)d_);                  \
    if constexpr (BN == 256)                                                             \
        gload16((const unsigned short*)(srcB1 + kb_), (unsigned short*)(d_ + 8192));     \
  } } while (0)

#define STAGE_AB(TILE, KH) do { STAGE_A(TILE, KH); STAGE_B(TILE, KH); } while (0)

#define VMW_N() do {                                                                     \
    if constexpr (BN == 256) asm volatile("s_waitcnt vmcnt(8)" ::: "memory");            \
    else                     asm volatile("s_waitcnt vmcnt(6)" ::: "memory");            \
  } while (0)

#define TAILVM() do {                                                                    \
    if (tail) asm volatile("s_waitcnt vmcnt(0)" ::: "memory");                           \
    else      VMW_N();                                                                   \
  } while (0)

#define VM_T(NT_, TL_) do {                                                              \
    if (tail) asm volatile("s_waitcnt vmcnt(" #TL_ ")" ::: "memory");                    \
    else      asm volatile("s_waitcnt vmcnt(" #NT_ ")" ::: "memory");                    \
  } while (0)

#define PHASE_G(PB, PKH, MBASE, MCNT, DOB, STAGE_STMT, VM_STMT) do {                     \
    const char* ab_ = RG(PB, PKH);                                                       \
    bf16_8 av_[MCNT];                                                                    \
    _Pragma("unroll")                                                                    \
    for (int mi_ = 0; mi_ < (MCNT); ++mi_)                                               \
        av_[mi_] = *(const bf16_8*)(ab_ + offA[(MBASE) + mi_]);                          \
    if (DOB) {                                                                           \
        _Pragma("unroll")                                                                \
        for (int nj_ = 0; nj_ < 4; ++nj_)                                                \
            bv[nj_] = *(const bf16_8*)(ab_ + 16384 + offB[nj_]);                         \
    }                                                                                    \
    STAGE_STMT;                                                                          \
    VM_STMT;                                                                             \
    __builtin_amdgcn_s_barrier();                                                        \
    __builtin_amdgcn_s_setprio(1);                                                       \
    _Pragma("unroll")                                                                    \
    for (int mi_ = 0; mi_ < (MCNT); ++mi_) {                                             \
        _Pragma("unroll")                                                                \
        for (int nj_ = 0; nj_ < 4; ++nj_)                                                \
            acc[(MBASE) + mi_][nj_] = __builtin_amdgcn_mfma_f32_16x16x32_bf16(           \
                av_[mi_], bv[nj_], acc[(MBASE) + mi_][nj_], 0, 0, 0);                    \
    }                                                                                    \
    __builtin_amdgcn_s_setprio(0);                                                       \
    asm volatile("s_waitcnt lgkmcnt(0)" ::: "memory");                                   \
    __builtin_amdgcn_s_barrier();                                                        \
  } while (0)

template <int BN, int WM, int WN, bool OUT_BF16, bool FUSE_T>
__global__ __launch_bounds__(512, 2) void k_gemm256(
    const unsigned short* __restrict__ A,   // [M][K] bf16
    const unsigned short* __restrict__ Bt,  // [N][K] bf16
    void* __restrict__ Cv,                  // [M][N]
    int N, int K, int nwgemm, int ntn,
    int tmx, int tnx, int ncc,              // 2D XCD sub-block geometry
    const float* __restrict__ TPin, unsigned short* __restrict__ TPout)
{
    extern __shared__ char smem[];
    constexpr int PWR = 256 / WM;        // per-wave rows of C
    constexpr int PWC = BN / WN;         // per-wave cols of C
    constexpr int MF  = PWR / 16;        // m fragments per wave
    constexpr int MF2 = MF / 2;
    constexpr int PR  = 16384 + BN * 64; // bytes per (buf,khalf) region: A 16K + B
    int t = threadIdx.x;

    if constexpr (FUSE_T) {
        if ((int)blockIdx.x >= nwgemm) {
            int tb = blockIdx.x - nwgemm;        // 0..63
            int half = t >> 8, lt = t & 255;
            unsigned short* tile = (unsigned short*)smem + half * (64 * 72);
            int r = lt >> 2, cs = (lt & 3) * 16, sw = (r >> 4) * 16;
            for (int i = 0; i < 32; ++i) {
                int tau = tb * 64 + i * 2 + half;
                int n0 = (tau & 63) * 64, k0 = (tau >> 6) * 64;
                const float* src = TPin + (size_t)(k0 + r) * 4096 + n0 + cs;
#pragma unroll
                for (int j = 0; j < 16; j += 4) {
                    float4 v = *reinterpret_cast<const float4*>(src + j);
                    tile[r * 72 + ((cs + j + 0) ^ sw)] = f2bf(v.x);
                    tile[r * 72 + ((cs + j + 1) ^ sw)] = f2bf(v.y);
                    tile[r * 72 + ((cs + j + 2) ^ sw)] = f2bf(v.z);
                    tile[r * 72 + ((cs + j + 3) ^ sw)] = f2bf(v.w);
                }
                __syncthreads();
                unsigned short tmp[16];
#pragma unroll
                for (int q = 0; q < 16; q++)
                    tmp[q] = tile[(cs + q) * 72 + (r ^ (((cs + q) >> 4) * 16))];
                unsigned short* dst = TPout + (size_t)(n0 + r) * 4096 + k0 + cs;
                *reinterpret_cast<ushort8v*>(dst) = *reinterpret_cast<const ushort8v*>(tmp);
                *reinterpret_cast<ushort8v*>(dst + 8) = *reinterpret_cast<const ushort8v*>(tmp + 8);
                __syncthreads();
            }
            return;
        }
    }

    const int NT = K >> 6;               // K-tiles of 64
    // 2D XCD sub-block swizzle: xcd owns a tmx x tnx block of tiles (bijective for
    // nwgemm = 8*tmx*tnx, ntn = ncc*tnx; verified GEMM1 4x6, GEMM2 4x8)
    int bid = blockIdx.x;
    int xcd = bid & 7, q = bid >> 3;
    int cr = xcd / ncc, cc = xcd - cr * ncc;
    int tm = cr * tmx + q / tnx;
    int tn = cc * tnx + q % tnx;
    int gm0 = tm << 8, gn0 = tn * BN;

    int w = t >> 6, lane = t & 63;
    int l15 = lane & 15, quad = lane >> 4;
    int wr = w / WN, wc = w % WN;
    int wby = w << 10;

    // per-lane swizzled ds_read byte offsets within a region
    int offA[MF], offB[4];
#pragma unroll
    for (int mh = 0; mh < 2; mh++)
#pragma unroll
        for (int mi = 0; mi < MF2; mi++) {
            int row = wr * PWR + mh * (PWR / 2) + mi * 16 + l15;
            offA[mh * MF2 + mi] = row * 64 + ((quad ^ ((row >> 1) & 3)) << 4);
        }
#pragma unroll
    for (int nj = 0; nj < 4; nj++) {
        int row = wc * PWC + nj * 16 + l15;
        offB[nj] = row * 64 + ((quad ^ ((row >> 1) & 3)) << 4);
    }

    // staging: linear LDS dest, inverse-swizzled global source
    int srow0 = t >> 2;                          // 0..127
    int sslot = (t & 3) ^ ((srow0 >> 1) & 3);
    const char* srcA0 = (const char*)A  + ((size_t)(gm0 + srow0)       * K + sslot * 8) * 2;
    const char* srcA1 = (const char*)A  + ((size_t)(gm0 + srow0 + 128) * K + sslot * 8) * 2;
    const char* srcB0 = (const char*)Bt + ((size_t)(gn0 + srow0)       * K + sslot * 8) * 2;
    const char* srcB1 = (BN == 256)
        ? (const char*)Bt + ((size_t)(gn0 + srow0 + 128) * K + sslot * 8) * 2
        : srcB0;

    f32x4 acc[MF][4] = {};
    bf16_8 bv[4];

    const int NITER = K >> 7;

    if constexpr (BN == 256) {
        // prologue: T0 fully + T1 khalf0 (12 loads)
        STAGE_A(0, 0); STAGE_B(0, 0);
        STAGE_A(0, 1); STAGE_B(0, 1);
        STAGE_A(1, 0); STAGE_B(1, 0);
        VMW_N();
        __builtin_amdgcn_s_barrier();
        for (int it = 0; it < NITER; ++it) {
            int T1 = 2 * it + 1, T2 = T1 + 1, T3 = T1 + 2;
            bool tail = (it == NITER - 1);
            PHASE_G(0, 0, 0,   MF2, 1, STAGE_A(T1, 1), ((void)0));
            PHASE_G(0, 0, MF2, MF2, 0, STAGE_B(T1, 1), VMW_N());
            PHASE_G(0, 1, 0,   MF2, 1, STAGE_A(T2, 0), ((void)0));
            PHASE_G(0, 1, MF2, MF2, 0, STAGE_B(T2, 0), TAILVM());
            PHASE_G(1, 0, 0,   MF2, 1, STAGE_A(T2, 1), ((void)0));
            PHASE_G(1, 0, MF2, MF2, 0, STAGE_B(T2, 1), VMW_N());
            PHASE_G(1, 1, 0,   MF2, 1, STAGE_A(T3, 0), ((void)0));
            PHASE_G(1, 1, MF2, MF2, 0, STAGE_B(T3, 0), VMW_N());
        }
    } else {
        // prologue: 3 stage units (9 loads)
        STAGE_AB(0, 0); STAGE_AB(0, 1); STAGE_AB(1, 0);
        asm volatile("s_waitcnt vmcnt(6)" ::: "memory");
        __builtin_amdgcn_s_barrier();
        for (int it = 0; it < NITER; ++it) {
            int T1 = 2 * it + 1, T2 = T1 + 1, T3 = T1 + 2;
            bool tail = (it == NITER - 1);
            PHASE_G(0, 0, 0, MF, 1, STAGE_AB(T1, 1),
                    asm volatile("s_waitcnt vmcnt(6)" ::: "memory"));
            PHASE_G(0, 1, 0, MF, 1, STAGE_AB(T2, 0), VM_T(6, 3));
            PHASE_G(1, 0, 0, MF, 1, STAGE_AB(T2, 1), VM_T(6, 0));
            PHASE_G(1, 1, 0, MF, 1, STAGE_AB(T3, 0), VM_T(6, 0));
        }
    }

    // epilogue
    int crow = gm0 + wr * PWR + quad * 4;
    int ccol = gn0 + wc * PWC + l15;
#pragma unroll
    for (int m = 0; m < MF; m++)
#pragma unroll
        for (int nj = 0; nj < 4; nj++)
#pragma unroll
            for (int r = 0; r < 4; r++) {
                size_t idx = (size_t)(crow + m * 16 + r) * N + (ccol + nj * 16);
                float v = acc[m][nj][r];
                if (OUT_BF16) ((unsigned short*)Cv)[idx] = f2bf(v);
                else          ((float*)Cv)[idx] = v;
            }
}

#undef RG
#undef STAGE_A
#undef STAGE_B
#undef STAGE_AB
#undef VMW_N
#undef TAILVM
#undef VM_T
#undef PHASE_G

// ---------- kernel 4: RoPE + head split; Q pre-scaled by (1/sqrt(128))*log2(e) ----------
__global__ void k_rope_split(const unsigned short* __restrict__ qkv,
                             unsigned short* __restrict__ Qb,
                             unsigned short* __restrict__ Kb)
{
    int wid = blockIdx.x * 4 + (threadIdx.x >> 6);
    int lane = threadIdx.x & 63;
    int head = wid % 40;
    int s = wid / 40;
    const unsigned short* src = qkv + (size_t)s * NQKV + head * HEADD;
    float x1 = bf2f(src[lane]);
    float x2 = bf2f(src[lane + 64]);
    float inv = __expf(-(float)lane * 0.14391156831212787f);
    float ang = (float)s * inv;
    float sn, c;
    __sincosf(ang, &sn, &c);
    float o1 = x1 * c - x2 * sn;
    float o2 = x1 * sn + x2 * c;
    unsigned short* dst;
    if (head < 32) {
        const float s2 = 0.12752908270648427f;  // (1/sqrt(128)) * log2(e) folded into Q
        o1 *= s2; o2 *= s2;
        dst = Qb + ((size_t)head * SEQ + s) * HEADD;
    } else {
        dst = Kb + ((size_t)(head - 32) * SEQ + s) * HEADD;
    }
    dst[lane] = f2bf(o1);
    dst[lane + 64] = f2bf(o2);
}

// ---------- kernel 5: pipelined causal flash attention (round-3 exact revert) ----------
// grid (8, 32); 512 thr / 8 waves; super-tile pair (b, 15-b) -> uniform 34 kv-iters.
// K/V double-buffered (2 x 32KB), global_load_lds linear dest + XOR-swizzled source;
// counted vmcnt(4). 83968 B LDS, launch_bounds(512,2). Best-measured config (474.4 total).
__global__ __launch_bounds__(512, 2) void k_attention(
    const unsigned short* __restrict__ Qb,  // [32][S][128], pre-scaled
    const unsigned short* __restrict__ Kb,  // [8][S][128]
    const unsigned short* __restrict__ Vt,  // [8*128][S]  (V transposed)
    unsigned short* __restrict__ Ob)        // [S][4096]
{
    extern __shared__ char smem[];          // [2][32768] K(16K)+V(16K) regions; Ps @65536
    unsigned short* Ps = (unsigned short*)(smem + 65536);
    int h = blockIdx.y, hkv = h >> 2;
    int b = blockIdx.x;                     // 0..7
    int t = threadIdx.x;
    int w = t >> 6, lane = t & 63, l15 = lane & 15, quad = lane >> 4;
    int x7 = l15 & 7;

    const char* kbase = (const char*)(Kb + (size_t)hkv * SEQ * HEADD);
    const char* vbase = (const char*)(Vt + (size_t)hkv * HEADD * SEQ);

    // staging constants: K rows 256B (16 slots), V rows 128B (8 slots)
    int rK0 = w * 4 + (lane >> 4), rK1 = rK0 + 32;
    size_t SK0 = (size_t)rK0 * 256 + (size_t)(((lane & 15) ^ (rK0 & 7)) << 4);
    size_t SK1 = (size_t)rK1 * 256 + (size_t)(((lane & 15) ^ (rK1 & 7)) << 4);
    int rV0 = w * 8 + (lane >> 3), rV1 = rV0 + 64;
    size_t SV0 = (size_t)rV0 * 4096 + (size_t)(((lane & 7) ^ (rV0 & 7)) << 4);
    size_t SV1 = (size_t)rV1 * 4096 + (size_t)(((lane & 7) ^ (rV1 & 7)) << 4);

    const int nA = 2 * b + 2;
    const int NI = 34;
    int qm0  = b * 128 + w * 16;            // phase-A wave q-base
    int qm0B = (15 - b) * 128 + w * 16;
    int qg  = qm0 + l15;
    int qgB = qm0B + l15;

    bf16_8 aq[4], aqB[4];
    {
        const unsigned short* qpA = Qb + ((size_t)h * SEQ + qg) * HEADD + quad * 8;
        const unsigned short* qpB = Qb + ((size_t)h * SEQ + qgB) * HEADD + quad * 8;
#pragma unroll
        for (int kk = 0; kk < 4; kk++) {
            aq[kk]  = *reinterpret_cast<const bf16_8*>(qpA + kk * 32);
            aqB[kk] = *reinterpret_cast<const bf16_8*>(qpB + kk * 32);
        }
    }

    f32x4 o[8] = {};
    float l_ = 0.f;

    // prologue: stage tile 0 -> region 0
    {
        char* dK = smem + w * 1024;
        gload16((const unsigned short*)(kbase + SK0), (unsigned short*)dK);
        gload16((const unsigned short*)(kbase + SK1), (unsigned short*)(dK + 8192));
        char* dV = smem + 16384 + w * 1024;
        gload16((const unsigned short*)(vbase + SV0), (unsigned short*)dV);
        gload16((const unsigned short*)(vbase + SV1), (unsigned short*)(dV + 8192));
    }

    for (int ii = 0; ii < NI; ++ii) {
        if (ii + 1 < NI) {
            int j = ii + 1;
            int kvn = (j < nA ? j : j - nA) << 6;
            const char* kb = kbase + (size_t)kvn * 256;
            const char* vb = vbase + (size_t)kvn * 2;
            char* dK = smem + (j & 1) * 32768 + w * 1024;
            gload16((const unsigned short*)(kb + SK0), (unsigned short*)dK);
            gload16((const unsigned short*)(kb + SK1), (unsigned short*)(dK + 8192));
            char* dV = smem + (j & 1) * 32768 + 16384 + w * 1024;
            gload16((const unsigned short*)(vb + SV0), (unsigned short*)dV);
            gload16((const unsigned short*)(vb + SV1), (unsigned short*)(dV + 8192));
            asm volatile("s_waitcnt vmcnt(4)" ::: "memory");
        } else {
            asm volatile("s_waitcnt vmcnt(0)" ::: "memory");
        }
        __builtin_amdgcn_s_barrier();

        if (ii == nA) {
            // phase-A epilogue (stores are older than next stage -> vmcnt(4) stays valid)
            float lr = l_;
            lr += __shfl_xor(lr, 16, 64);
            lr += __shfl_xor(lr, 32, 64);
            float rinv = 1.0f / lr;
            unsigned short* orow = Ob + (size_t)qg * (NHEADS * HEADD) + h * HEADD + quad * 4;
#pragma unroll
            for (int dt = 0; dt < 8; dt++) {
                ushort4v pk = { f2bf(o[dt][0] * rinv), f2bf(o[dt][1] * rinv),
                                f2bf(o[dt][2] * rinv), f2bf(o[dt][3] * rinv) };
                *reinterpret_cast<ushort4v*>(orow + dt * 16) = pk;
            }
#pragma unroll
            for (int kk = 0; kk < 4; kk++) aq[kk] = aqB[kk];
            qm0 = qm0B; qg = qgB;
#pragma unroll
            for (int dt = 0; dt < 8; dt++) o[dt] = (f32x4){0.f, 0.f, 0.f, 0.f};
            l_ = 0.f;
        }

        int kv0 = (ii < nA ? ii : ii - nA) << 6;
        const unsigned short* Kbuf = (const unsigned short*)(smem + (ii & 1) * 32768);
        const unsigned short* Vbuf = Kbuf + 8192;

        if (kv0 <= qm0 + 15) {
            f32x4 sc[4];
#pragma unroll
            for (int nt = 0; nt < 4; nt++) {
                f32x4 z = {};
#pragma unroll
                for (int kk = 0; kk < 4; kk++) {
                    bf16_8 bk = *reinterpret_cast<const bf16_8*>(
                        &Kbuf[(nt * 16 + l15) * 128 + (((kk * 4 + quad) ^ x7) << 3)]);
                    z = __builtin_amdgcn_mfma_f32_16x16x32_bf16(bk, aq[kk], z, 0, 0, 0);
                }
                sc[nt] = z;
            }
            bool needMask = (kv0 + 63 > qm0);
#pragma unroll
            for (int nt = 0; nt < 4; nt++)
#pragma unroll
                for (int r = 0; r < 4; r++) {
                    float a = sc[nt][r] - 12.0f;   // fixed shift, no running max
                    if (needMask) {
                        int kg = kv0 + nt * 16 + quad * 4 + r;
                        if (kg > qg) a = -1000.0f;
                    }
                    float p = EXP2(a);
                    sc[nt][r] = p;
                    l_ += p;
                }
            unsigned short* prow = Ps + (w * 16 + l15) * 72;
#pragma unroll
            for (int nt = 0; nt < 4; nt++) {
                ushort4v pk = { f2bf(sc[nt][0]), f2bf(sc[nt][1]), f2bf(sc[nt][2]), f2bf(sc[nt][3]) };
                *reinterpret_cast<ushort4v*>(prow + nt * 16 + quad * 4) = pk;
            }
            asm volatile("s_waitcnt lgkmcnt(0)" ::: "memory");
            bf16_8 pf[2];
#pragma unroll
            for (int kk = 0; kk < 2; kk++)
                pf[kk] = *reinterpret_cast<const bf16_8*>(prow + kk * 32 + quad * 8);
#pragma unroll
            for (int dt = 0; dt < 8; dt++)
#pragma unroll
                for (int kk = 0; kk < 2; kk++) {
                    bf16_8 av = *reinterpret_cast<const bf16_8*>(
                        &Vbuf[(dt * 16 + l15) * 64 + (((kk * 4 + quad) ^ x7) << 3)]);
                    o[dt] = __builtin_amdgcn_mfma_f32_16x16x32_bf16(av, pf[kk], o[dt], 0, 0, 0);
                }
        }
        asm volatile("s_waitcnt lgkmcnt(0)" ::: "memory");
        __builtin_amdgcn_s_barrier();
    }

    // phase-B epilogue
    l_ += __shfl_xor(l_, 16, 64);
    l_ += __shfl_xor(l_, 32, 64);
    float rinv = 1.0f / l_;
    unsigned short* orow = Ob + (size_t)qg * (NHEADS * HEADD) + h * HEADD + quad * 4;
#pragma unroll
    for (int dt = 0; dt < 8; dt++) {
        ushort4v pk = { f2bf(o[dt][0] * rinv), f2bf(o[dt][1] * rinv),
                        f2bf(o[dt][2] * rinv), f2bf(o[dt][3] * rinv) };
        *reinterpret_cast<ushort4v*>(orow + dt * 16) = pk;
    }
}

// ---------- launch ----------
extern "C" void kernel_launch(void* const* d_in, const int* in_sizes, int n_in,
                              void* d_out, int out_size, void* d_ws, size_t ws_size,
                              hipStream_t stream) {
    const float* hs    = (const float*)d_in[0];
    const float* w_qkv = (const float*)d_in[1];
    const float* w_o   = (const float*)d_in[2];

    static bool s_attr_set = false;
    if (!s_attr_set) {
        hipFuncSetAttribute(reinterpret_cast<const void*>(k_gemm256<256, 2, 4, true, true>),
                            hipFuncAttributeMaxDynamicSharedMemorySize, 131072);
        hipFuncSetAttribute(reinterpret_cast<const void*>(k_gemm256<128, 4, 2, false, false>),
                            hipFuncAttributeMaxDynamicSharedMemorySize, 131072);
        hipFuncSetAttribute(reinterpret_cast<const void*>(k_attention),
                            hipFuncAttributeMaxDynamicSharedMemorySize, 131072);
        s_attr_set = true;
    }

    char* ws = (char*)d_ws;
    size_t off = 0;
    auto alloc = [&](size_t bytes) -> void* {
        void* p = ws + off;
        off += (bytes + 255) & ~(size_t)255;
        return p;
    };
    unsigned short* Xb    = (unsigned short*)alloc((size_t)SEQ * HDIM * 2);
    unsigned short* R1    = (unsigned short*)alloc((size_t)NQKV * HDIM * 2);
    unsigned short* Wot   = (unsigned short*)alloc((size_t)HDIM * HDIM * 2);
    unsigned short* QKVb  = (unsigned short*)alloc((size_t)SEQ * NQKV * 2);
    unsigned short* Wqkvt = R1;
    unsigned short* Qb = R1;
    unsigned short* Kb = Qb + (size_t)NHEADS * SEQ * HEADD;
    unsigned short* Vt = Kb + (size_t)NKVH * SEQ * HEADD;
    unsigned short* AOb = Xb;

    k_f32_to_bf16<<<(SEQ * HDIM) / 1024, 256, 0, stream>>>(hs, Xb, SEQ * HDIM);
    k_transpose_f32_to_bf16<<<dim3(NQKV / 64, HDIM / 64), 256, 0, stream>>>(w_qkv, Wqkvt, HDIM, NQKV);
    // GEMM1: 192 gemm blocks (2D XCD blocks 4tm x 6tn) + 64 transpose helpers
    k_gemm256<256, 2, 4, true, true><<<dim3(256), dim3(512), 131072, stream>>>(
        Xb, Wqkvt, QKVb, NQKV, HDIM, 192, NQKV / 256, 4, 6, 4, w_o, Wot);
    k_rope_split<<<(SEQ * 40) / 4, 256, 0, stream>>>(QKVb, Qb, Kb);
    k_transpose_bf16<<<dim3((NKVH * HEADD) / 64, SEQ / 64), 256, 0, stream>>>(
        QKVb + (size_t)(NHEADS + NKVH) * HEADD, Vt, NQKV, SEQ);
    // attention: round-3 exact (83968 B LDS, (512,2))
    k_attention<<<dim3(8, NHEADS), dim3(512), 83968, stream>>>(Qb, Kb, Vt, AOb);
    // GEMM2: 256x128 tiles, 256 wgs, 2D XCD blocks 4tm x 8tn
    k_gemm256<128, 4, 2, false, false><<<dim3(256), dim3(512), 98304, stream>>>(
        AOb, Wot, d_out, HDIM, HDIM, 256, HDIM / 128, 4, 8, 4, nullptr, nullptr);
}